// Round 1
// 268.920 us; speedup vs baseline: 1.0179x; 1.0179x over previous
//
#include <hip/hip_runtime.h>

typedef __attribute__((ext_vector_type(8))) short short8;
typedef __attribute__((ext_vector_type(4))) float f32x4;
typedef __attribute__((ext_vector_type(4))) int i32x4;
typedef __attribute__((ext_vector_type(4))) unsigned short u16x4;
typedef __attribute__((ext_vector_type(8))) unsigned short u16x8;
typedef __attribute__((ext_vector_type(2))) unsigned int u32x2;

#define B_  4
#define N_  2048
#define D_  512
#define H_  8
#define DH_ 64
#define M_  (B_ * N_)   // 8192

__device__ __forceinline__ unsigned short f2bf(float f) {
    union { float f; unsigned u; } un; un.f = f;
    unsigned r = un.u + 0x7FFFu + ((un.u >> 16) & 1u);
    return (unsigned short)(r >> 16);
}
__device__ __forceinline__ unsigned packbf(float lo, float hi) {
    union { float f; unsigned u; } a, b;
    a.f = lo; b.f = hi;
    return __builtin_amdgcn_perm(b.u + 0x8000u, a.u + 0x8000u, 0x07060302u);
}
__device__ __forceinline__ float lo16f(unsigned u) {
    union { unsigned u; float f; } un; un.u = u << 16; return un.f;
}
__device__ __forceinline__ float hi16f(unsigned u) {
    union { unsigned u; float f; } un; un.u = u & 0xFFFF0000u; return un.f;
}
__device__ __forceinline__ float exp2fast(float x) {
#if __has_builtin(__builtin_amdgcn_exp2f)
    return __builtin_amdgcn_exp2f(x);
#else
    float r; asm("v_exp_f32 %0, %1" : "=v"(r) : "v"(x)); return r;
#endif
}

typedef __attribute__((address_space(1))) const void gvoid;
typedef __attribute__((address_space(3))) void svoid;
__device__ __forceinline__ void load16_lds(const void* g, void* s) {
    __builtin_amdgcn_global_load_lds((gvoid*)g, (svoid*)s, 16, 0, 0);
}

// ---------------------------------------------------------------------------
// fp32 -> bf16 conversions
// ---------------------------------------------------------------------------
__global__ __launch_bounds__(256) void cvt_x(const float* __restrict__ src,
                                             unsigned short* __restrict__ dst) {
    const int i = (blockIdx.x * 256 + threadIdx.x) * 4;
    f32x4 v = *(const f32x4*)(src + i);
    u16x4 o;
    o[0] = f2bf(v[0]); o[1] = f2bf(v[1]); o[2] = f2bf(v[2]); o[3] = f2bf(v[3]);
    *(u16x4*)(dst + i) = o;
}

// bias fp32 [b][q][kv] -> bf16*log2e TILED: Bt[b][q/32][kv/64][q&31][kv&63]
// (scaled by log2(e) so attention softmax can run in exp2 domain)
__global__ __launch_bounds__(256) void cvt_bias(const float* __restrict__ src,
                                                unsigned short* __restrict__ dst) {
    const size_t i = ((size_t)blockIdx.x * 256 + threadIdx.x) * 8;
    const int kv = (int)(i & 2047);
    const int q  = (int)((i >> 11) & 2047);
    const int b  = (int)(i >> 22);
    const float L2E = 1.4426950408889634f;
    f32x4 v0 = *(const f32x4*)(src + i);
    f32x4 v1 = *(const f32x4*)(src + i + 4);
    u16x8 o;
    o[0] = f2bf(v0[0] * L2E); o[1] = f2bf(v0[1] * L2E);
    o[2] = f2bf(v0[2] * L2E); o[3] = f2bf(v0[3] * L2E);
    o[4] = f2bf(v1[0] * L2E); o[5] = f2bf(v1[1] * L2E);
    o[6] = f2bf(v1[2] * L2E); o[7] = f2bf(v1[3] * L2E);
    const size_t oi = ((((size_t)b * 64 + (q >> 5)) * 32 + (kv >> 6)) * 32 + (q & 31)) * 64 + (kv & 63);
    *(u16x8*)(dst + oi) = o;
}

__global__ __launch_bounds__(256) void cvt_w(const float* __restrict__ W0,
                                             const float* __restrict__ W1,
                                             const float* __restrict__ W2,
                                             const float* __restrict__ W3,
                                             unsigned short* __restrict__ dst) {
    const int sel = blockIdx.y;
    const float* src = (sel == 0) ? W0 : (sel == 1) ? W1 : (sel == 2) ? W2 : W3;
    unsigned short* d = dst + (size_t)sel * D_ * D_;
    const int i = (blockIdx.x * 256 + threadIdx.x) * 4;
    f32x4 v = *(const f32x4*)(src + i);
    u16x4 o;
    o[0] = f2bf(v[0]); o[1] = f2bf(v[1]); o[2] = f2bf(v[2]); o[3] = f2bf(v[3]);
    *(u16x4*)(d + i) = o;
}

// ---------------------------------------------------------------------------
// NT GEMM with global_load_lds(16B) staging + XOR-swizzled LDS.
// Tile 128x128, BK=32, 4 waves; optional fused per-head LN.
// ---------------------------------------------------------------------------
template <bool F32OUT, bool LNF>
__global__ __launch_bounds__(256, 2) void gemm_nt(
    const unsigned short* __restrict__ A,
    const unsigned short* __restrict__ W,     // [nsel][512][512]
    const float* __restrict__ Bv0,
    const float* __restrict__ Bv1,
    const float* __restrict__ Bv2,
    const float* __restrict__ g0, const float* __restrict__ be0,
    const float* __restrict__ g1, const float* __restrict__ be1,
    unsigned short* __restrict__ outb,
    float* __restrict__ outf)
{
    const int mt = blockIdx.x;
    const int nt = blockIdx.y;
    const int sel = nt >> 2;
    const unsigned short* Wp = W + (size_t)sel * D_ * D_;
    const float* Bv = (sel == 0) ? Bv0 : (sel == 1) ? Bv1 : Bv2;
    const int n0 = (nt & 3) * 128;

    __shared__ __align__(16) unsigned short As[128 * 32];
    __shared__ __align__(16) unsigned short Bs[128 * 32];

    const int tid = threadIdx.x;
    const int w   = tid >> 6;
    const int l   = tid & 63;
    const int l15 = l & 15;
    const int qd  = l >> 4;
    const int wr  = w >> 1;
    const int wc  = w & 1;

    int srow[2], scol[2];
#pragma unroll
    for (int c = 0; c < 2; ++c) {
        const int g   = (w * 2 + c) * 64 + l;
        const int row = g >> 2;
        srow[c] = row;
        scol[c] = ((g & 3) ^ (row & 3)) * 8;
    }

    f32x4 acc[4][4];
#pragma unroll
    for (int i = 0; i < 4; ++i)
#pragma unroll
        for (int j = 0; j < 4; ++j)
            acc[i][j] = (f32x4){0.f, 0.f, 0.f, 0.f};

    const int swz = qd ^ (l15 & 3);

    for (int k0 = 0; k0 < D_; k0 += 32) {
        __syncthreads();
#pragma unroll
        for (int c = 0; c < 2; ++c) {
            load16_lds(A  + (size_t)(mt * 128 + srow[c]) * D_ + k0 + scol[c],
                       As + (w * 2 + c) * 512);
            load16_lds(Wp + (size_t)(n0 + srow[c]) * D_ + k0 + scol[c],
                       Bs + (w * 2 + c) * 512);
        }
        __syncthreads();

        short8 af[4], bfr[4];
#pragma unroll
        for (int rt = 0; rt < 4; ++rt)
            af[rt] = *(const short8*)&As[(wr * 64 + rt * 16 + l15) * 32 + swz * 8];
#pragma unroll
        for (int ct = 0; ct < 4; ++ct)
            bfr[ct] = *(const short8*)&Bs[(wc * 64 + ct * 16 + l15) * 32 + swz * 8];
#pragma unroll
        for (int rt = 0; rt < 4; ++rt)
#pragma unroll
            for (int ct = 0; ct < 4; ++ct)
                acc[rt][ct] = __builtin_amdgcn_mfma_f32_16x16x32_bf16(
                    af[rt], bfr[ct], acc[rt][ct], 0, 0, 0);
    }

    const float* gam = (sel == 0) ? g0 : g1;
    const float* bet = (sel == 0) ? be0 : be1;
    float gv[4], bv2[4];
    if (LNF) {
#pragma unroll
        for (int ct = 0; ct < 4; ++ct) { gv[ct] = gam[ct * 16 + l15]; bv2[ct] = bet[ct * 16 + l15]; }
    }

#pragma unroll
    for (int rt = 0; rt < 4; ++rt) {
        float v[4][4];
#pragma unroll
        for (int ct = 0; ct < 4; ++ct) {
            const float bias = Bv[n0 + wc * 64 + ct * 16 + l15];
#pragma unroll
            for (int r = 0; r < 4; ++r) v[ct][r] = acc[rt][ct][r] + bias;
        }
        if (LNF && sel < 2) {
#pragma unroll
            for (int r = 0; r < 4; ++r) {
                float s  = v[0][r] + v[1][r] + v[2][r] + v[3][r];
                float s2 = v[0][r]*v[0][r] + v[1][r]*v[1][r] + v[2][r]*v[2][r] + v[3][r]*v[3][r];
#pragma unroll
                for (int o = 1; o <= 8; o <<= 1) {
                    s  += __shfl_xor(s, o);
                    s2 += __shfl_xor(s2, o);
                }
                const float mu  = s * 0.015625f;
                const float var = s2 * 0.015625f - mu * mu;
                const float rs  = rsqrtf(var + 1e-6f);
#pragma unroll
                for (int ct = 0; ct < 4; ++ct)
                    v[ct][r] = (v[ct][r] - mu) * rs * gv[ct] + bv2[ct];
            }
        }
#pragma unroll
        for (int ct = 0; ct < 4; ++ct) {
            const int col  = n0 + wc * 64 + ct * 16 + l15;
            const int row0 = mt * 128 + wr * 64 + rt * 16 + qd * 4;
#pragma unroll
            for (int r = 0; r < 4; ++r) {
                const size_t oidx = (size_t)(row0 + r) * D_ + col;
                if (F32OUT) outf[oidx] = v[ct][r];
                else        outb[(size_t)sel * M_ * D_ + oidx] = f2bf(v[ct][r]);
            }
        }
    }
}

// ---------------------------------------------------------------------------
// pack_kv: K[b*N+n][512] -> Kt[b][h][nt][kv64][dh64] (8KB contiguous tiles)
//          V[b*N+n][512] -> Vt2[b][h][nt][dh64][kv64] (transposed tiles)
// ---------------------------------------------------------------------------
__global__ __launch_bounds__(256) void pack_kv(
    const unsigned short* __restrict__ K, const unsigned short* __restrict__ V,
    unsigned short* __restrict__ Kt, unsigned short* __restrict__ Vt2)
{
    const int nt = blockIdx.x, b = blockIdx.y;
    const int tid = threadIdx.x;
    __shared__ __align__(16) unsigned short Vl[64][520];

#pragma unroll
    for (int i = 0; i < 16; ++i) {
        const int c = i * 256 + tid;         // 0..4095
        const int row = c >> 6, ch = c & 63;
        const size_t srow = ((size_t)(b * N_ + nt * 64 + row)) * D_ + ch * 8;
        i32x4 kd = *(const i32x4*)(K + srow);
        const int h = ch >> 3, dc = ch & 7;
        *(i32x4*)(Kt + ((((size_t)(b * 8 + h) * 32 + nt) * 64 + row) * 64) + dc * 8) = kd;
        i32x4 vd = *(const i32x4*)(V + srow);
        *(i32x4*)&Vl[row][ch * 8] = vd;
    }
    __syncthreads();
#pragma unroll
    for (int i = 0; i < 16; ++i) {
        const int c = i * 256 + tid;
        const int h = c >> 9, r = c & 511;
        const int dh = r >> 3, kc = r & 7;
        u16x8 o;
#pragma unroll
        for (int j = 0; j < 8; ++j) o[j] = Vl[kc * 8 + j][h * 64 + dh];
        *(u16x8*)(Vt2 + ((((size_t)(b * 8 + h) * 32 + nt) * 64 + dh) * 64) + kc * 8) = o;
    }
}

// ---------------------------------------------------------------------------
// attn8: 4 waves x 32 q-rows (128 q) per block, one (b,h). kv loop over 32
// tiles of 64. Pipelined: K/V double-buffered in LDS (global_load_lds issued
// one tile ahead, counted vmcnt(8), single raw s_barrier per iter); bias
// prefetched one tile ahead into REGISTERS (2-deep, static via 2-unroll).
// Softmax in exp2 domain (log2e folded into scale + bias at cvt time).
// s_setprio(1) around both MFMA clusters.
// LDS: K0 8K | V0 8K | K1 8K | V1 8K | Pw 4*32*72*2 = 51200 B (unchanged).
// ---------------------------------------------------------------------------
__global__ __launch_bounds__(256, 2) void attn8(
    const unsigned short* __restrict__ Qm,
    const unsigned short* __restrict__ Kt,
    const unsigned short* __restrict__ Vt2,
    const unsigned short* __restrict__ Bt,
    unsigned short* __restrict__ AO)
{
    const int qt = blockIdx.x;   // 0..15
    const int h  = blockIdx.y;   // 0..7
    const int b  = blockIdx.z;   // 0..3
    const int w  = threadIdx.x >> 6;
    const int l  = threadIdx.x & 63;
    const int l15 = l & 15;
    const int qd  = l >> 4;
    const int q0 = qt * 128 + w * 32;

    __shared__ __align__(16) unsigned char smem[51200];
    unsigned short* PwB = (unsigned short*)(smem + 32768) + w * 32 * 72;

    // staging lane constants (row-XOR pre-swizzled global source, linear LDS)
    int sc[2], soff[2];
#pragma unroll
    for (int i = 0; i < 2; ++i) {
        const int c = (w * 2 + i) * 64 + l;
        const int row = c >> 3, g = c & 7;
        sc[i] = c;
        soff[i] = row * 64 + (g ^ (row & 7)) * 8;
    }

    // Q fragments (B-operand): n=q(ct*16+l15), k=dh(hf*32+qd*8+j)
    short8 qf[2][2];
#pragma unroll
    for (int ct = 0; ct < 2; ++ct)
#pragma unroll
        for (int hf = 0; hf < 2; ++hf)
            qf[ct][hf] = *(const short8*)(Qm +
                (size_t)(b * N_ + q0 + ct * 16 + l15) * D_ + h * DH_ + hf * 32 + qd * 8);

    f32x4 Ot[4][2];
#pragma unroll
    for (int rt = 0; rt < 4; ++rt)
#pragma unroll
        for (int ct = 0; ct < 2; ++ct) Ot[rt][ct] = (f32x4){0.f, 0.f, 0.f, 0.f};
    float m_i[2] = {-3.0e38f, -3.0e38f};
    float l_i[2] = {0.f, 0.f};   // lane-partial

    const unsigned short* Ktile0 = Kt  + (((size_t)(b * 8 + h) * 32) * 64) * 64;
    const unsigned short* Vtile0 = Vt2 + (((size_t)(b * 8 + h) * 32) * 64) * 64;
    const unsigned short* Btile0 = Bt  + (((size_t)b * 64 + qt * 4 + w) * 32) * 2048;

    // prologue: stage tile 0 K/V into buf0, bias tile 0 into brA, then drain
#pragma unroll
    for (int i = 0; i < 2; ++i) {
        load16_lds(Ktile0 + soff[i], smem + sc[i] * 16);
        load16_lds(Vtile0 + soff[i], smem + 8192 + sc[i] * 16);
    }
    u32x2 brA[4][2], brB[4][2];
#pragma unroll
    for (int rt = 0; rt < 4; ++rt)
#pragma unroll
        for (int ct = 0; ct < 2; ++ct)
            brA[rt][ct] = *(const u32x2*)(Btile0 + (ct * 16 + l15) * 64 + rt * 16 + qd * 4);
    asm volatile("s_waitcnt vmcnt(0)" ::: "memory");

// One iteration of the kv loop. CUR selects the LDS K/V buffer (compile-time
// per unrolled copy). BRC = bias regs for this tile (loaded last iter),
// BRN = bias regs to prefetch for the next tile.
// vmcnt invariant at loop top: in-flight = gll(this tile)(4, oldest) +
// bias(this tile... already consumed) -> after prev softmax wait:
// gll_kt(4) + bias_kt(8). vmcnt(8) retires exactly gll_kt (in-order).
#define ATTN_ITER(KT, CUR, BRC, BRN) do {                                      \
    unsigned char* Kbc = smem + (CUR) * 16384;                                 \
    unsigned char* Vbc = Kbc + 8192;                                           \
    asm volatile("s_waitcnt vmcnt(8)" ::: "memory");                           \
    __builtin_amdgcn_s_barrier();                                              \
    __builtin_amdgcn_sched_barrier(0);                                         \
    if ((KT) < 31) {                                                           \
        const unsigned short* Kn = Ktile0 + (size_t)((KT) + 1) * 4096;         \
        const unsigned short* Vn = Vtile0 + (size_t)((KT) + 1) * 4096;         \
        unsigned char* KbN = smem + (((CUR) ^ 1)) * 16384;                     \
        _Pragma("unroll")                                                      \
        for (int i = 0; i < 2; ++i) {                                          \
            load16_lds(Kn + soff[i], KbN + sc[i] * 16);                        \
            load16_lds(Vn + soff[i], KbN + 8192 + sc[i] * 16);                 \
        }                                                                      \
    }                                                                          \
    asm volatile("" ::: "memory");  /* pin order: gll before bias loads */     \
    {                                                                          \
        const unsigned short* Bn = Btile0 +                                    \
            (size_t)(((KT) < 31) ? (KT) + 1 : 31) * 2048;                      \
        _Pragma("unroll")                                                      \
        for (int rt = 0; rt < 4; ++rt)                                         \
            _Pragma("unroll")                                                  \
            for (int ct = 0; ct < 2; ++ct)                                     \
                BRN[rt][ct] = *(const u32x2*)(Bn + (ct * 16 + l15) * 64 +      \
                                              rt * 16 + qd * 4);               \
    }                                                                          \
    short8 kf[4][2];                                                           \
    _Pragma("unroll")                                                          \
    for (int rt = 0; rt < 4; ++rt) {                                           \
        const int kv = rt * 16 + l15;                                          \
        _Pragma("unroll")                                                      \
        for (int hf = 0; hf < 2; ++hf) {                                       \
            const int cidx = (hf * 4 + qd) ^ (kv & 7);                         \
            kf[rt][hf] = *(const short8*)(Kbc + kv * 128 + cidx * 16);         \
        }                                                                      \
    }                                                                          \
    f32x4 St[4][2];                                                            \
    __builtin_amdgcn_s_setprio(1);                                             \
    _Pragma("unroll")                                                          \
    for (int rt = 0; rt < 4; ++rt)                                             \
        _Pragma("unroll")                                                      \
        for (int ct = 0; ct < 2; ++ct) {                                       \
            f32x4 v = (f32x4){0.f, 0.f, 0.f, 0.f};                             \
            v = __builtin_amdgcn_mfma_f32_16x16x32_bf16(kf[rt][0], qf[ct][0], v, 0, 0, 0); \
            v = __builtin_amdgcn_mfma_f32_16x16x32_bf16(kf[rt][1], qf[ct][1], v, 0, 0, 0); \
            St[rt][ct] = v;                                                    \
        }                                                                      \
    __builtin_amdgcn_s_setprio(0);                                             \
    short8 vf[4][2];                                                           \
    _Pragma("unroll")                                                          \
    for (int rt = 0; rt < 4; ++rt) {                                           \
        const int dh = rt * 16 + l15;                                          \
        _Pragma("unroll")                                                      \
        for (int hf = 0; hf < 2; ++hf) {                                       \
            const int cidx = (hf * 4 + qd) ^ (dh & 7);                         \
            vf[rt][hf] = *(const short8*)(Vbc + dh * 128 + cidx * 16);         \
        }                                                                      \
    }                                                                          \
    _Pragma("unroll")                                                          \
    for (int ct = 0; ct < 2; ++ct) {                                           \
        float sv[4][4];                                                        \
        float mx = -3.0e38f;                                                   \
        _Pragma("unroll")                                                      \
        for (int rt = 0; rt < 4; ++rt) {                                       \
            sv[rt][0] = St[rt][ct][0] * 0.1803368801f + lo16f(BRC[rt][ct][0]); \
            sv[rt][1] = St[rt][ct][1] * 0.1803368801f + hi16f(BRC[rt][ct][0]); \
            sv[rt][2] = St[rt][ct][2] * 0.1803368801f + lo16f(BRC[rt][ct][1]); \
            sv[rt][3] = St[rt][ct][3] * 0.1803368801f + hi16f(BRC[rt][ct][1]); \
            _Pragma("unroll")                                                  \
            for (int r = 0; r < 4; ++r) mx = fmaxf(mx, sv[rt][r]);             \
        }                                                                      \
        mx = fmaxf(mx, __shfl_xor(mx, 16));                                    \
        mx = fmaxf(mx, __shfl_xor(mx, 32));                                    \
        const float mnew  = fmaxf(m_i[ct], mx);                                \
        const float alpha = exp2fast(m_i[ct] - mnew);                          \
        float rsum = 0.f;                                                      \
        _Pragma("unroll")                                                      \
        for (int rt = 0; rt < 4; ++rt) {                                       \
            const float p0 = exp2fast(sv[rt][0] - mnew);                       \
            const float p1 = exp2fast(sv[rt][1] - mnew);                       \
            const float p2 = exp2fast(sv[rt][2] - mnew);                       \
            const float p3 = exp2fast(sv[rt][3] - mnew);                       \
            rsum += (p0 + p1) + (p2 + p3);                                     \
            u32x2 pw; pw[0] = packbf(p0, p1); pw[1] = packbf(p2, p3);          \
            *(u32x2*)&PwB[(ct * 16 + l15) * 72 + rt * 16 + qd * 4] = pw;       \
        }                                                                      \
        l_i[ct] = l_i[ct] * alpha + rsum;                                      \
        m_i[ct] = mnew;                                                        \
        _Pragma("unroll")                                                      \
        for (int rt = 0; rt < 4; ++rt)                                         \
            _Pragma("unroll")                                                  \
            for (int r = 0; r < 4; ++r) Ot[rt][ct][r] *= alpha;                \
    }                                                                          \
    short8 pf[2][2];                                                           \
    _Pragma("unroll")                                                          \
    for (int ct = 0; ct < 2; ++ct)                                             \
        _Pragma("unroll")                                                      \
        for (int hf = 0; hf < 2; ++hf)                                         \
            pf[ct][hf] = *(const short8*)&PwB[(ct * 16 + l15) * 72 + hf * 32 + qd * 8]; \
    __builtin_amdgcn_s_setprio(1);                                             \
    _Pragma("unroll")                                                          \
    for (int rt = 0; rt < 4; ++rt)                                             \
        _Pragma("unroll")                                                      \
        for (int ct = 0; ct < 2; ++ct) {                                       \
            Ot[rt][ct] = __builtin_amdgcn_mfma_f32_16x16x32_bf16(vf[rt][0], pf[ct][0], Ot[rt][ct], 0, 0, 0); \
            Ot[rt][ct] = __builtin_amdgcn_mfma_f32_16x16x32_bf16(vf[rt][1], pf[ct][1], Ot[rt][ct], 0, 0, 0); \
        }                                                                      \
    __builtin_amdgcn_s_setprio(0);                                             \
} while (0)

    for (int kt2 = 0; kt2 < 16; ++kt2) {
        ATTN_ITER(kt2 * 2,     0, brA, brB);
        ATTN_ITER(kt2 * 2 + 1, 1, brB, brA);
    }
#undef ATTN_ITER

    // epilogue
#pragma unroll
    for (int ct = 0; ct < 2; ++ct) {
        l_i[ct] += __shfl_xor(l_i[ct], 16);
        l_i[ct] += __shfl_xor(l_i[ct], 32);
        const float inv = 1.f / l_i[ct];
        const int q = q0 + ct * 16 + l15;
#pragma unroll
        for (int rt = 0; rt < 4; ++rt) {
            u16x4 ob;
#pragma unroll
            for (int r = 0; r < 4; ++r) ob[r] = f2bf(Ot[rt][ct][r] * inv);
            *(u16x4*)(AO + (size_t)(b * N_ + q) * D_ + h * DH_ + rt * 16 + qd * 4) = ob;
        }
    }
}

// ---------------------------------------------------------------------------
extern "C" void kernel_launch(void* const* d_in, const int* in_sizes, int n_in,
                              void* d_out, int out_size, void* d_ws, size_t ws_size,
                              hipStream_t stream) {
    const float* x  = (const float*)d_in[0];
    const float* ab = (const float*)d_in[1];
    const float* Wq = (const float*)d_in[2];
    const float* bq = (const float*)d_in[3];
    const float* Wk = (const float*)d_in[4];
    const float* bk = (const float*)d_in[5];
    const float* Wv = (const float*)d_in[6];
    const float* bv = (const float*)d_in[7];
    const float* Wo = (const float*)d_in[8];
    const float* bo = (const float*)d_in[9];
    const float* qg = (const float*)d_in[10];
    const float* qb = (const float*)d_in[11];
    const float* kg = (const float*)d_in[12];
    const float* kb = (const float*)d_in[13];

    // ws layout (bf16 elements)
    unsigned short* xb  = (unsigned short*)d_ws;                // [8192][512]
    unsigned short* Wb  = xb  + (size_t)M_ * D_;                // [4][512][512]
    unsigned short* Y   = Wb  + (size_t)4 * D_ * D_;            // [3][8192][512]
    unsigned short* Kt  = Y   + (size_t)3 * M_ * D_;            // [4][8][32][64][64]
    unsigned short* Vt2 = Kt  + (size_t)M_ * D_;                // [4][8][32][64][64]
    unsigned short* AO  = Vt2 + (size_t)M_ * D_;                // [8192][512]
    unsigned short* Bt  = AO  + (size_t)M_ * D_;                // [4][64][32][32][64]
    float* out = (float*)d_out;

    cvt_x<<<dim3(M_ * D_ / 1024), dim3(256), 0, stream>>>(x, xb);
    cvt_w<<<dim3(D_ * D_ / 1024, 4), dim3(256), 0, stream>>>(Wq, Wk, Wv, Wo, Wb);
    cvt_bias<<<dim3((int)((size_t)B_ * N_ * N_ / 2048)), dim3(256), 0, stream>>>(ab, Bt);

    // QKV projection with fused per-head LN on q,k
    gemm_nt<false, true><<<dim3(64, 12), dim3(256), 0, stream>>>(
        xb, Wb, bq, bk, bv, qg, qb, kg, kb, Y, nullptr);

    // pack K,V into contiguous per-head tiles (V transposed)
    pack_kv<<<dim3(32, 4), dim3(256), 0, stream>>>(
        Y + (size_t)M_ * D_, Y + (size_t)2 * M_ * D_, Kt, Vt2);

    // attention (pipelined, double-buffered)
    attn8<<<dim3(16, 8, 4), dim3(256), 0, stream>>>(
        Y, Kt, Vt2, Bt, AO);

    // output projection -> d_out (fp32)
    gemm_nt<true, false><<<dim3(64, 4), dim3(256), 0, stream>>>(
        AO, Wb + (size_t)3 * D_ * D_, bo, bo, bo,
        nullptr, nullptr, nullptr, nullptr, nullptr, out);
}

// Round 2
// 254.752 us; speedup vs baseline: 1.0745x; 1.0556x over previous
//
#include <hip/hip_runtime.h>

typedef __attribute__((ext_vector_type(8))) short short8;
typedef __attribute__((ext_vector_type(4))) float f32x4;
typedef __attribute__((ext_vector_type(4))) int i32x4;
typedef __attribute__((ext_vector_type(4))) unsigned short u16x4;
typedef __attribute__((ext_vector_type(8))) unsigned short u16x8;
typedef __attribute__((ext_vector_type(2))) unsigned int u32x2;

#define B_  4
#define N_  2048
#define D_  512
#define H_  8
#define DH_ 64
#define M_  (B_ * N_)   // 8192

__device__ __forceinline__ unsigned short f2bf(float f) {
    union { float f; unsigned u; } un; un.f = f;
    unsigned r = un.u + 0x7FFFu + ((un.u >> 16) & 1u);
    return (unsigned short)(r >> 16);
}
__device__ __forceinline__ unsigned packbf(float lo, float hi) {
    union { float f; unsigned u; } a, b;
    a.f = lo; b.f = hi;
    return __builtin_amdgcn_perm(b.u + 0x8000u, a.u + 0x8000u, 0x07060302u);
}
__device__ __forceinline__ float exp2fast(float x) {
#if __has_builtin(__builtin_amdgcn_exp2f)
    return __builtin_amdgcn_exp2f(x);
#else
    float r; asm("v_exp_f32 %0, %1" : "=v"(r) : "v"(x)); return r;
#endif
}

typedef __attribute__((address_space(1))) const void gvoid;
typedef __attribute__((address_space(3))) void svoid;
__device__ __forceinline__ void load16_lds(const void* g, void* s) {
    __builtin_amdgcn_global_load_lds((gvoid*)g, (svoid*)s, 16, 0, 0);
}

// ---------------------------------------------------------------------------
// fp32 -> bf16 conversions for x and the 4 weight matrices, one launch.
// blocks [0,4096): x (8192x512). blocks [4096,5120): W (4x512x512).
// ---------------------------------------------------------------------------
__global__ __launch_bounds__(256) void cvt_all(
    const float* __restrict__ x,
    const float* __restrict__ W0, const float* __restrict__ W1,
    const float* __restrict__ W2, const float* __restrict__ W3,
    unsigned short* __restrict__ xb, unsigned short* __restrict__ Wb) {
    const int bx = blockIdx.x;
    const float* src;
    unsigned short* dst;
    int i;
    if (bx < 4096) {
        src = x; dst = xb;
        i = (bx * 256 + (int)threadIdx.x) * 4;
    } else {
        const int r = bx - 4096;
        const int sel = r >> 8;
        src = (sel == 0) ? W0 : (sel == 1) ? W1 : (sel == 2) ? W2 : W3;
        dst = Wb + (size_t)sel * D_ * D_;
        i = ((r & 255) * 256 + (int)threadIdx.x) * 4;
    }
    f32x4 v = *(const f32x4*)(src + i);
    u16x4 o;
    o[0] = f2bf(v[0]); o[1] = f2bf(v[1]); o[2] = f2bf(v[2]); o[3] = f2bf(v[3]);
    *(u16x4*)(dst + i) = o;
}

// ---------------------------------------------------------------------------
// NT GEMM with global_load_lds(16B) staging + XOR-swizzled LDS.
// Tile 128x128, BK=32, 4 waves; optional fused per-head LN.
// ---------------------------------------------------------------------------
template <bool F32OUT, bool LNF>
__global__ __launch_bounds__(256, 2) void gemm_nt(
    const unsigned short* __restrict__ A,
    const unsigned short* __restrict__ W,     // [nsel][512][512]
    const float* __restrict__ Bv0,
    const float* __restrict__ Bv1,
    const float* __restrict__ Bv2,
    const float* __restrict__ g0, const float* __restrict__ be0,
    const float* __restrict__ g1, const float* __restrict__ be1,
    unsigned short* __restrict__ outb,
    float* __restrict__ outf)
{
    const int mt = blockIdx.x;
    const int nt = blockIdx.y;
    const int sel = nt >> 2;
    const unsigned short* Wp = W + (size_t)sel * D_ * D_;
    const float* Bv = (sel == 0) ? Bv0 : (sel == 1) ? Bv1 : Bv2;
    const int n0 = (nt & 3) * 128;

    __shared__ __align__(16) unsigned short As[128 * 32];
    __shared__ __align__(16) unsigned short Bs[128 * 32];

    const int tid = threadIdx.x;
    const int w   = tid >> 6;
    const int l   = tid & 63;
    const int l15 = l & 15;
    const int qd  = l >> 4;
    const int wr  = w >> 1;
    const int wc  = w & 1;

    int srow[2], scol[2];
#pragma unroll
    for (int c = 0; c < 2; ++c) {
        const int g   = (w * 2 + c) * 64 + l;
        const int row = g >> 2;
        srow[c] = row;
        scol[c] = ((g & 3) ^ (row & 3)) * 8;
    }

    f32x4 acc[4][4];
#pragma unroll
    for (int i = 0; i < 4; ++i)
#pragma unroll
        for (int j = 0; j < 4; ++j)
            acc[i][j] = (f32x4){0.f, 0.f, 0.f, 0.f};

    const int swz = qd ^ (l15 & 3);

    for (int k0 = 0; k0 < D_; k0 += 32) {
        __syncthreads();
#pragma unroll
        for (int c = 0; c < 2; ++c) {
            load16_lds(A  + (size_t)(mt * 128 + srow[c]) * D_ + k0 + scol[c],
                       As + (w * 2 + c) * 512);
            load16_lds(Wp + (size_t)(n0 + srow[c]) * D_ + k0 + scol[c],
                       Bs + (w * 2 + c) * 512);
        }
        __syncthreads();

        short8 af[4], bfr[4];
#pragma unroll
        for (int rt = 0; rt < 4; ++rt)
            af[rt] = *(const short8*)&As[(wr * 64 + rt * 16 + l15) * 32 + swz * 8];
#pragma unroll
        for (int ct = 0; ct < 4; ++ct)
            bfr[ct] = *(const short8*)&Bs[(wc * 64 + ct * 16 + l15) * 32 + swz * 8];
#pragma unroll
        for (int rt = 0; rt < 4; ++rt)
#pragma unroll
            for (int ct = 0; ct < 4; ++ct)
                acc[rt][ct] = __builtin_amdgcn_mfma_f32_16x16x32_bf16(
                    af[rt], bfr[ct], acc[rt][ct], 0, 0, 0);
    }

    const float* gam = (sel == 0) ? g0 : g1;
    const float* bet = (sel == 0) ? be0 : be1;
    float gv[4], bv2[4];
    if (LNF) {
#pragma unroll
        for (int ct = 0; ct < 4; ++ct) { gv[ct] = gam[ct * 16 + l15]; bv2[ct] = bet[ct * 16 + l15]; }
    }

#pragma unroll
    for (int rt = 0; rt < 4; ++rt) {
        float v[4][4];
#pragma unroll
        for (int ct = 0; ct < 4; ++ct) {
            const float bias = Bv[n0 + wc * 64 + ct * 16 + l15];
#pragma unroll
            for (int r = 0; r < 4; ++r) v[ct][r] = acc[rt][ct][r] + bias;
        }
        if (LNF && sel < 2) {
#pragma unroll
            for (int r = 0; r < 4; ++r) {
                float s  = v[0][r] + v[1][r] + v[2][r] + v[3][r];
                float s2 = v[0][r]*v[0][r] + v[1][r]*v[1][r] + v[2][r]*v[2][r] + v[3][r]*v[3][r];
#pragma unroll
                for (int o = 1; o <= 8; o <<= 1) {
                    s  += __shfl_xor(s, o);
                    s2 += __shfl_xor(s2, o);
                }
                const float mu  = s * 0.015625f;
                const float var = s2 * 0.015625f - mu * mu;
                const float rs  = rsqrtf(var + 1e-6f);
#pragma unroll
                for (int ct = 0; ct < 4; ++ct)
                    v[ct][r] = (v[ct][r] - mu) * rs * gv[ct] + bv2[ct];
            }
        }
#pragma unroll
        for (int ct = 0; ct < 4; ++ct) {
            const int col  = n0 + wc * 64 + ct * 16 + l15;
            const int row0 = mt * 128 + wr * 64 + rt * 16 + qd * 4;
#pragma unroll
            for (int r = 0; r < 4; ++r) {
                const size_t oidx = (size_t)(row0 + r) * D_ + col;
                if (F32OUT) outf[oidx] = v[ct][r];
                else        outb[(size_t)sel * M_ * D_ + oidx] = f2bf(v[ct][r]);
            }
        }
    }
}

// ---------------------------------------------------------------------------
// pack_kv: K[b*N+n][512] -> Kt[b][h][nt][kv64][dh64] (8KB contiguous tiles)
//          V[b*N+n][512] -> Vt2[b][h][nt][dh64][kv64] (transposed tiles)
// ---------------------------------------------------------------------------
__global__ __launch_bounds__(256) void pack_kv(
    const unsigned short* __restrict__ K, const unsigned short* __restrict__ V,
    unsigned short* __restrict__ Kt, unsigned short* __restrict__ Vt2)
{
    const int nt = blockIdx.x, b = blockIdx.y;
    const int tid = threadIdx.x;
    __shared__ __align__(16) unsigned short Vl[64][520];

#pragma unroll
    for (int i = 0; i < 16; ++i) {
        const int c = i * 256 + tid;         // 0..4095
        const int row = c >> 6, ch = c & 63;
        const size_t srow = ((size_t)(b * N_ + nt * 64 + row)) * D_ + ch * 8;
        i32x4 kd = *(const i32x4*)(K + srow);
        const int h = ch >> 3, dc = ch & 7;
        *(i32x4*)(Kt + ((((size_t)(b * 8 + h) * 32 + nt) * 64 + row) * 64) + dc * 8) = kd;
        i32x4 vd = *(const i32x4*)(V + srow);
        *(i32x4*)&Vl[row][ch * 8] = vd;
    }
    __syncthreads();
#pragma unroll
    for (int i = 0; i < 16; ++i) {
        const int c = i * 256 + tid;
        const int h = c >> 9, r = c & 511;
        const int dh = r >> 3, kc = r & 7;
        u16x8 o;
#pragma unroll
        for (int j = 0; j < 8; ++j) o[j] = Vl[kc * 8 + j][h * 64 + dh];
        *(u16x8*)(Vt2 + ((((size_t)(b * 8 + h) * 32 + nt) * 64 + dh) * 64) + kc * 8) = o;
    }
}

// ---------------------------------------------------------------------------
// attn9: 8 waves x 16 q-rows (128 q) per block, one (b,h). 512 threads.
// Occupancy: 2 blocks/CU x 8 waves = 16 waves/CU (4/SIMD) vs 8 before.
// K/V double-buffered in LDS (global_load_lds one tile ahead, counted
// vmcnt(4), single raw s_barrier per iter). fp32 bias loaded DIRECTLY from
// the input tensor into registers, prefetched one tile ahead (2-deep,
// static via 2-unroll). Softmax in exp2 domain. setprio(1) around MFMA.
// LDS: K0 8K | V0 8K | K1 8K | V1 8K | Pw 8*16*72*2 = 51200 B.
// ---------------------------------------------------------------------------
__global__ __launch_bounds__(512, 4) void attn9(
    const unsigned short* __restrict__ Qm,
    const unsigned short* __restrict__ Kt,
    const unsigned short* __restrict__ Vt2,
    const float* __restrict__ Bias,          // [b][q][kv] fp32
    unsigned short* __restrict__ AO)
{
    const int qt = blockIdx.x;   // 0..15
    const int h  = blockIdx.y;   // 0..7
    const int b  = blockIdx.z;   // 0..3
    const int w  = threadIdx.x >> 6;   // 0..7
    const int l  = threadIdx.x & 63;
    const int l15 = l & 15;
    const int qd  = l >> 4;
    const int q0 = qt * 128 + w * 16;

    __shared__ __align__(16) unsigned char smem[51200];
    unsigned short* PwB = (unsigned short*)(smem + 32768) + w * 16 * 72;

    // staging lane constants (row-XOR pre-swizzled global source, linear LDS)
    const int c    = w * 64 + l;            // 0..511 granules of 16B
    const int srow = c >> 3;
    const int sg   = (c & 7) ^ (srow & 7);
    const int soff = srow * 64 + sg * 8;    // shorts
    const int sc16 = c * 16;                // LDS byte offset

    // Q fragments (B-operand): n=q(l15), k=dh(hf*32+qd*8+j)
    short8 qf[2];
#pragma unroll
    for (int hf = 0; hf < 2; ++hf)
        qf[hf] = *(const short8*)(Qm +
            (size_t)(b * N_ + q0 + l15) * D_ + h * DH_ + hf * 32 + qd * 8);

    f32x4 Ot[4];
#pragma unroll
    for (int rt = 0; rt < 4; ++rt) Ot[rt] = (f32x4){0.f, 0.f, 0.f, 0.f};
    float m_i = -3.0e38f;
    float l_i = 0.f;   // lane-partial

    const unsigned short* Ktile0 = Kt  + (((size_t)(b * 8 + h) * 32) * 64) * 64;
    const unsigned short* Vtile0 = Vt2 + (((size_t)(b * 8 + h) * 32) * 64) * 64;
    const float* biasQ = Bias + ((size_t)b * N_ + q0 + l15) * N_;   // this lane's q-row

    // prologue: stage tile 0 K/V into buf0, bias tile 0 into brA, then drain
    load16_lds(Ktile0 + soff, smem + sc16);
    load16_lds(Vtile0 + soff, smem + 8192 + sc16);
    f32x4 brA[4], brB[4];
#pragma unroll
    for (int rt = 0; rt < 4; ++rt)
        brA[rt] = *(const f32x4*)(biasQ + rt * 16 + qd * 4);
    asm volatile("s_waitcnt vmcnt(0)" ::: "memory");

// One kv-tile iteration. CUR = LDS buffer (compile-time). BRC = fp32 bias
// regs for this tile (loaded last iter), BRN = prefetch target for next.
// vmcnt at loop top: in-flight = [gll(kt) x2 (oldest), bias(kt) x4];
// vmcnt(4) retires exactly the 2 gll (in-order queue).
#define ATTN_ITER(KT, CUR, BRC, BRN) do {                                      \
    unsigned char* Kbc = smem + (CUR) * 16384;                                 \
    unsigned char* Vbc = Kbc + 8192;                                           \
    asm volatile("s_waitcnt vmcnt(4)" ::: "memory");                           \
    __builtin_amdgcn_s_barrier();                                              \
    __builtin_amdgcn_sched_barrier(0);                                         \
    if ((KT) < 31) {                                                           \
        const unsigned short* Kn = Ktile0 + (size_t)((KT) + 1) * 4096;         \
        const unsigned short* Vn = Vtile0 + (size_t)((KT) + 1) * 4096;         \
        unsigned char* KbN = smem + (((CUR) ^ 1)) * 16384;                     \
        load16_lds(Kn + soff, KbN + sc16);                                     \
        load16_lds(Vn + soff, KbN + 8192 + sc16);                              \
    }                                                                          \
    asm volatile("" ::: "memory");  /* pin order: gll before bias loads */     \
    {                                                                          \
        const float* Bn = biasQ + (size_t)(((KT) < 31) ? (KT) + 1 : 31) * 64;  \
        _Pragma("unroll")                                                      \
        for (int rt = 0; rt < 4; ++rt)                                         \
            BRN[rt] = *(const f32x4*)(Bn + rt * 16 + qd * 4);                  \
    }                                                                          \
    short8 kf[4][2];                                                           \
    _Pragma("unroll")                                                          \
    for (int rt = 0; rt < 4; ++rt) {                                           \
        const int kv = rt * 16 + l15;                                          \
        _Pragma("unroll")                                                      \
        for (int hf = 0; hf < 2; ++hf) {                                       \
            const int cidx = (hf * 4 + qd) ^ (kv & 7);                         \
            kf[rt][hf] = *(const short8*)(Kbc + kv * 128 + cidx * 16);         \
        }                                                                      \
    }                                                                          \
    f32x4 St[4];                                                               \
    __builtin_amdgcn_s_setprio(1);                                             \
    _Pragma("unroll")                                                          \
    for (int rt = 0; rt < 4; ++rt) {                                           \
        f32x4 v = (f32x4){0.f, 0.f, 0.f, 0.f};                                 \
        v = __builtin_amdgcn_mfma_f32_16x16x32_bf16(kf[rt][0], qf[0], v, 0, 0, 0); \
        v = __builtin_amdgcn_mfma_f32_16x16x32_bf16(kf[rt][1], qf[1], v, 0, 0, 0); \
        St[rt] = v;                                                            \
    }                                                                          \
    __builtin_amdgcn_s_setprio(0);                                             \
    short8 vf[4][2];                                                           \
    _Pragma("unroll")                                                          \
    for (int rt = 0; rt < 4; ++rt) {                                           \
        const int dh = rt * 16 + l15;                                          \
        _Pragma("unroll")                                                      \
        for (int hf = 0; hf < 2; ++hf) {                                       \
            const int cidx = (hf * 4 + qd) ^ (dh & 7);                         \
            vf[rt][hf] = *(const short8*)(Vbc + dh * 128 + cidx * 16);         \
        }                                                                      \
    }                                                                          \
    {                                                                          \
        float sv[4][4];                                                        \
        float mx = -3.0e38f;                                                   \
        _Pragma("unroll")                                                      \
        for (int rt = 0; rt < 4; ++rt) {                                       \
            _Pragma("unroll")                                                  \
            for (int r = 0; r < 4; ++r) {                                      \
                sv[rt][r] = St[rt][r] * 0.1803368801f +                        \
                            BRC[rt][r] * 1.4426950408889634f;                  \
                mx = fmaxf(mx, sv[rt][r]);                                     \
            }                                                                  \
        }                                                                      \
        mx = fmaxf(mx, __shfl_xor(mx, 16));                                    \
        mx = fmaxf(mx, __shfl_xor(mx, 32));                                    \
        const float mnew  = fmaxf(m_i, mx);                                    \
        const float alpha = exp2fast(m_i - mnew);                              \
        float rsum = 0.f;                                                      \
        _Pragma("unroll")                                                      \
        for (int rt = 0; rt < 4; ++rt) {                                       \
            const float p0 = exp2fast(sv[rt][0] - mnew);                       \
            const float p1 = exp2fast(sv[rt][1] - mnew);                       \
            const float p2 = exp2fast(sv[rt][2] - mnew);                       \
            const float p3 = exp2fast(sv[rt][3] - mnew);                       \
            rsum += (p0 + p1) + (p2 + p3);                                     \
            u32x2 pw; pw[0] = packbf(p0, p1); pw[1] = packbf(p2, p3);          \
            *(u32x2*)&PwB[l15 * 72 + rt * 16 + qd * 4] = pw;                   \
        }                                                                      \
        l_i = l_i * alpha + rsum;                                              \
        m_i = mnew;                                                            \
        _Pragma("unroll")                                                      \
        for (int rt = 0; rt < 4; ++rt)                                         \
            _Pragma("unroll")                                                  \
            for (int r = 0; r < 4; ++r) Ot[rt][r] *= alpha;                    \
    }                                                                          \
    short8 pf[2];                                                              \
    _Pragma("unroll")                                                          \
    for (int hf = 0; hf < 2; ++hf)                                             \
        pf[hf] = *(const short8*)&PwB[l15 * 72 + hf * 32 + qd * 8];            \
    __builtin_amdgcn_s_setprio(1);                                             \
    _Pragma("unroll")                                                          \
    for (int rt = 0; rt < 4; ++rt) {                                           \
        Ot[rt] = __builtin_amdgcn_mfma_f32_16x16x32_bf16(vf[rt][0], pf[0], Ot[rt], 0, 0, 0); \
        Ot[rt] = __builtin_amdgcn_mfma_f32_16x16x32_bf16(vf[rt][1], pf[1], Ot[rt], 0, 0, 0); \
    }                                                                          \
    __builtin_amdgcn_s_setprio(0);                                             \
} while (0)

    for (int kt2 = 0; kt2 < 16; ++kt2) {
        ATTN_ITER(kt2 * 2,     0, brA, brB);
        ATTN_ITER(kt2 * 2 + 1, 1, brB, brA);
    }
#undef ATTN_ITER

    // epilogue
    l_i += __shfl_xor(l_i, 16);
    l_i += __shfl_xor(l_i, 32);
    const float inv = 1.f / l_i;
    const int q = q0 + l15;
#pragma unroll
    for (int rt = 0; rt < 4; ++rt) {
        u16x4 ob;
#pragma unroll
        for (int r = 0; r < 4; ++r) ob[r] = f2bf(Ot[rt][r] * inv);
        *(u16x4*)(AO + (size_t)(b * N_ + q) * D_ + h * DH_ + rt * 16 + qd * 4) = ob;
    }
}

// ---------------------------------------------------------------------------
extern "C" void kernel_launch(void* const* d_in, const int* in_sizes, int n_in,
                              void* d_out, int out_size, void* d_ws, size_t ws_size,
                              hipStream_t stream) {
    const float* x  = (const float*)d_in[0];
    const float* ab = (const float*)d_in[1];
    const float* Wq = (const float*)d_in[2];
    const float* bq = (const float*)d_in[3];
    const float* Wk = (const float*)d_in[4];
    const float* bk = (const float*)d_in[5];
    const float* Wv = (const float*)d_in[6];
    const float* bv = (const float*)d_in[7];
    const float* Wo = (const float*)d_in[8];
    const float* bo = (const float*)d_in[9];
    const float* qg = (const float*)d_in[10];
    const float* qb = (const float*)d_in[11];
    const float* kg = (const float*)d_in[12];
    const float* kb = (const float*)d_in[13];

    // ws layout (bf16 elements)
    unsigned short* xb  = (unsigned short*)d_ws;                // [8192][512]
    unsigned short* Wb  = xb  + (size_t)M_ * D_;                // [4][512][512]
    unsigned short* Y   = Wb  + (size_t)4 * D_ * D_;            // [3][8192][512]
    unsigned short* Kt  = Y   + (size_t)3 * M_ * D_;            // [4][8][32][64][64]
    unsigned short* Vt2 = Kt  + (size_t)M_ * D_;                // [4][8][32][64][64]
    unsigned short* AO  = Vt2 + (size_t)M_ * D_;                // [8192][512]
    float* out = (float*)d_out;

    cvt_all<<<dim3(5120), dim3(256), 0, stream>>>(x, Wq, Wk, Wv, Wo, xb, Wb);

    // QKV projection with fused per-head LN on q,k
    gemm_nt<false, true><<<dim3(64, 12), dim3(256), 0, stream>>>(
        xb, Wb, bq, bk, bv, qg, qb, kg, kb, Y, nullptr);

    // pack K,V into contiguous per-head tiles (V transposed)
    pack_kv<<<dim3(32, 4), dim3(256), 0, stream>>>(
        Y + (size_t)M_ * D_, Y + (size_t)2 * M_ * D_, Kt, Vt2);

    // attention (8 waves/block, fp32 bias direct from input)
    attn9<<<dim3(16, 8, 4), dim3(512), 0, stream>>>(
        Y, Kt, Vt2, ab, AO);

    // output projection -> d_out (fp32)
    gemm_nt<true, false><<<dim3(64, 4), dim3(256), 0, stream>>>(
        AO, Wb + (size_t)3 * D_ * D_, bo, bo, bo,
        nullptr, nullptr, nullptr, nullptr, nullptr, out);
}